// Round 1
// baseline (160.318 us; speedup 1.0000x reference)
//
#include <hip/hip_runtime.h>
#include <hip/hip_fp16.h>
#include <math.h>

#define EPS 0.05f
#define INV_EPS 20.0f
#define BIGF 1e30f

typedef short bf16x8 __attribute__((ext_vector_type(8)));
typedef float f32x4 __attribute__((ext_vector_type(4)));

__device__ __forceinline__ unsigned f2bf(float x) {
  unsigned u = __float_as_uint(x);
  return (u + 0x7fffu + ((u >> 16) & 1u)) >> 16;  // RNE f32->bf16
}
__device__ __forceinline__ unsigned pk2(float a, float b) {
  return (f2bf(a) & 0xffffu) | (f2bf(b) << 16);
}

// ---- LDS arena (bytes). Aliasing by phase lifetime (unchanged layout):
#define S_HSA  0        // short[128][72] = 18432
#define S_HSB  18432    //              -> 36864
#define S_GM   0        // half[128][130] = 33280 (alias)
#define S_KT   0        // float[112][52] = 23296 (alias)
#define S_KR   36864    // float[48][116] = 22272 -> 59136
#define S_DIAG 59136    // f32[128] -> 59648
#define S_IA   59648    // int[48]  -> 59840
#define S_IB   59840    // int[112] -> 60288
#define S_RV   60288    // f32[48]  -> 60480
#define S_CV   60480    // f32[112] -> 60928
#define S_UV   60928    // f32[48]  -> 61120
#define S_VV   61120    // f32[112] -> 61568
#define S_CNT  61568    // int[4]   -> 61584
#define S_RED  61584    // f32[8]   -> 61616
#define SMEM_SZ 61632

#define LOAD4(F0, F1, F2, F3, ptr) do { \
  F0 = *(const float4*)(ptr);      F1 = *(const float4*)((ptr) + 4); \
  F2 = *(const float4*)((ptr) + 8); F3 = *(const float4*)((ptr) + 12); \
} while (0)

#define PACK_STORE(dst, F0, F1, F2, F3) do { \
  uint4 w0, w1; \
  w0.x = pk2(F0.x, F0.y); w0.y = pk2(F0.z, F0.w); \
  w0.z = pk2(F1.x, F1.y); w0.w = pk2(F1.z, F1.w); \
  w1.x = pk2(F2.x, F2.y); w1.y = pk2(F2.z, F2.w); \
  w1.z = pk2(F3.x, F3.y); w1.w = pk2(F3.z, F3.w); \
  *(uint4*)((dst) + srow * 72 + sc0) = w0; \
  *(uint4*)((dst) + srow * 72 + sc0 + 8) = w1; \
} while (0)

__global__ __launch_bounds__(512, 2)
void k_mega(const float* __restrict__ H, const int* __restrict__ ttid,
            const int* __restrict__ amask,
            const float* __restrict__ Wc, const float* __restrict__ bc,
            const float* __restrict__ Ws, const float* __restrict__ bs,
            const float* __restrict__ gate,
            const float* __restrict__ lnw, const float* __restrict__ lnb,
            const float* __restrict__ Wcls, const float* __restrict__ bcls,
            float* __restrict__ dcross, float* __restrict__ cnt,
            float* __restrict__ fused, unsigned* ticket,
            float* __restrict__ out)
{
  __shared__ __align__(16) char smem[SMEM_SZ];
  __shared__ int smflag;
  const int t = threadIdx.x;
  const int bid = blockIdx.x;

  if (bid < 64) {
    // ================= compact-support Sinkhorn =================
    const int b = bid;
    short*  HsA  = (short*)(smem + S_HSA);
    short*  HsB  = (short*)(smem + S_HSB);
    __half* Gm   = (__half*)(smem + S_GM);
    float*  KT   = (float*)(smem + S_KT);
    float*  Kr   = (float*)(smem + S_KR);
    float*  diag = (float*)(smem + S_DIAG);
    int*    ia   = (int*)(smem + S_IA);
    int*    ib   = (int*)(smem + S_IB);
    float*  rv   = (float*)(smem + S_RV);
    float*  cv   = (float*)(smem + S_CV);
    float*  uv   = (float*)(smem + S_UV);
    float*  vv   = (float*)(smem + S_VV);
    int*    cnts = (int*)(smem + S_CNT);

    const int lane = t & 63;
    const int w = t >> 6;

    // issue the first two H chunks early (overlap with Phase A)
    const float* Hb = H + (size_t)b * (128 * 768);
    const int srow = t >> 2, sc0 = (t & 3) * 16;
    const float* srcB = Hb + srow * 768 + sc0;
    float4 fA0, fA1, fA2, fA3, fB0, fB1, fB2, fB3;
    LOAD4(fA0, fA1, fA2, fA3, srcB);        // chunk 0
    LOAD4(fB0, fB1, fB2, fB3, srcB + 64);   // chunk 1

    // ---- Phase A: compact index lists via ballot prefix-sum ----
    int flagA = 0, flagB = 0;
    unsigned long long mA = 0, mB = 0;
    if (t < 128) {
      int a_ = amask[b*128 + t], tt_ = ttid[b*128 + t];
      flagA = (a_ == 1 && tt_ == 0);
      flagB = (a_ == 1 && tt_ == 1);
      mA = __ballot(flagA);
      mB = __ballot(flagB);
      if (lane == 0) { cnts[w] = __popcll(mA); cnts[2 + w] = __popcll(mB); }
    }
    __syncthreads();
    const int n0 = cnts[0] + cnts[1];
    const int n1 = cnts[2] + cnts[3];
    if (t < 128) {
      int offA = (w == 1) ? cnts[0] : 0;
      int offB = (w == 1) ? cnts[2] : 0;
      unsigned long long below = (1ull << lane) - 1ull;
      if (flagA) ia[offA + __popcll(mA & below)] = t;
      if (flagB) ib[offB + __popcll(mB & below)] = t;
    }

    // ---- Phase B: Gram = H_b H_b^T, bf16 MFMA, double-buffered staging ----
    const int wv = t >> 6;
    const int fm = lane & 15, fg = lane >> 4;
    f32x4 acc[8];
    #pragma unroll
    for (int ct = 0; ct < 8; ct++) {
      acc[ct][0] = 0.f; acc[ct][1] = 0.f; acc[ct][2] = 0.f; acc[ct][3] = 0.f;
    }
    PACK_STORE(HsA, fA0, fA1, fA2, fA3);    // chunk 0 -> HsA

    for (int kc = 0; kc < 12; kc++) {
      __syncthreads();     // tile kc visible in cur; prior reads of nxt done
      short* cur = (kc & 1) ? HsB : HsA;
      short* nxt = (kc & 1) ? HsA : HsB;
      if (kc < 10) {       // issue prefetch of chunk kc+2 (before pack/store)
        const float* s2 = srcB + (kc + 2) * 64;
        if ((kc & 1) == 0) LOAD4(fA0, fA1, fA2, fA3, s2);
        else               LOAD4(fB0, fB1, fB2, fB3, s2);
      }
      if (kc < 11) {       // store chunk kc+1 into the other buffer
        if ((kc & 1) == 0) PACK_STORE(nxt, fB0, fB1, fB2, fB3);
        else               PACK_STORE(nxt, fA0, fA1, fA2, fA3);
      }
      #pragma unroll
      for (int ks = 0; ks < 2; ks++) {
        bf16x8 afrag = *(const bf16x8*)(cur + (wv * 16 + fm) * 72 + ks * 32 + fg * 8);
        #pragma unroll
        for (int ct = 0; ct < 8; ct++) {
          bf16x8 bfrag = *(const bf16x8*)(cur + (ct * 16 + fm) * 72 + ks * 32 + fg * 8);
          acc[ct] = __builtin_amdgcn_mfma_f32_16x16x32_bf16(afrag, bfrag, acc[ct], 0, 0, 0);
        }
      }
    }
    __syncthreads();       // all MFMA reads done; Hs region now dead -> Gm
    #pragma unroll
    for (int ct = 0; ct < 8; ct++) {
      int gc = ct * 16 + fm;
      #pragma unroll
      for (int q2 = 0; q2 < 4; q2++) {
        int gr = wv * 16 + fg * 4 + q2;
        Gm[gr * 130 + gc] = __float2half(acc[ct][q2]);
      }
    }
    if ((fm >> 2) == fg) diag[wv * 16 + fm] = acc[wv][fm & 3];  // f32 diag
    for (int e = t; e < 48 * 116; e += 512) Kr[e] = BIGF;
    __syncthreads();

    // ---- Phase C: compact Ce, shifts r/c, K transform, KT build ----
    for (int i = t >> 7; i < n0; i += 4) {
      int ra = ia[i];
      float di = diag[ra];
      for (int j = t & 127; j < n1; j += 128) {
        int cb = ib[j];
        float g = __half2float(Gm[ra * 130 + cb]);
        float d2 = fmaxf(di + diag[cb] - 2.0f * g, 1e-6f);
        Kr[i * 116 + j] = sqrtf(d2) * INV_EPS;
      }
    }
    __syncthreads();
    if (t < 192) {  // r_i = min_j Ce
      int r = t >> 2, c = t & 3;
      const float* row = Kr + r * 116 + c * 28;
      float mn = BIGF;
      #pragma unroll
      for (int g = 0; g < 7; g++) {
        float4 x = *(const float4*)(row + g * 4);
        mn = fminf(mn, fminf(fminf(x.x, x.y), fminf(x.z, x.w)));
      }
      mn = fminf(mn, __shfl_xor(mn, 1));
      mn = fminf(mn, __shfl_xor(mn, 2));
      if (c == 0) rv[r] = mn;
    }
    __syncthreads();
    if (t < 448) {  // c_j = min_{i<n0} (Ce - r_i)
      int cl = t >> 2, rr = t & 3;
      float mn = BIGF;
      #pragma unroll
      for (int g = 0; g < 12; g++) {
        int i = rr * 12 + g;
        float v = (i < n0) ? (Kr[i * 116 + cl] - rv[i]) : BIGF;
        mn = fminf(mn, v);
      }
      mn = fminf(mn, __shfl_xor(mn, 1));
      mn = fminf(mn, __shfl_xor(mn, 2));
      if (rr == 0) cv[cl] = mn;
    }
    __syncthreads();
    for (int i = t >> 7; i < 48; i += 4) {  // K = exp(min(r+c-Ce,0)), in place
      float ri = rv[i];
      for (int j = t & 127; j < 112; j += 128) {
        float ce = Kr[i * 116 + j];
        Kr[i * 116 + j] = __expf(fminf(ri + cv[j] - ce, 0.f));
      }
    }
    __syncthreads();       // Gm dead -> KT
    for (int i = t >> 7; i < 48; i += 4) {  // col-major copy for v-step
      int j = t & 127;
      if (j < 112) KT[j * 52 + i] = Kr[i * 116 + j];
    }
    const float inv_n0 = 1.0f / (float)n0;
    const float inv_n1 = 1.0f / (float)n1;
    if (t < 112) vv[t] = (t < n1) ? inv_n1 * __expf(-cv[t]) : 0.f;
    __syncthreads();       // last barrier before Phase D

    // ---- Phase D: single-wave, K register-resident, 30 scaling iterations ----
    if (t < 64) {
      const int l = t;
      const int r48 = (l < 48) ? l : 47;           // clamp (masked later)
      const float a_l = (l < n0) ? inv_n0 : 0.f;
      const int j2ok = (l + 64 < 112);
      const int c2 = j2ok ? (l + 64) : l;          // clamp (masked later)
      const float b1w = (l < n1) ? inv_n1 : 0.f;
      const float b2w = (j2ok && c2 < n1) ? inv_n1 : 0.f;
      const float* Krow = Kr + r48 * 116;
      const float* Kc1p = KT + l * 52;
      const float* Kc2p = KT + c2 * 52;

      // hoist loop-invariant K into registers (28+12+12 float4 = 208 VGPR)
      float4 kr[28], kc1[12], kc2[12];
      #pragma unroll
      for (int g = 0; g < 28; g++) kr[g] = *(const float4*)(Krow + 4 * g);
      #pragma unroll
      for (int g = 0; g < 12; g++) {
        kc1[g] = *(const float4*)(Kc1p + 4 * g);
        kc2[g] = *(const float4*)(Kc2p + 4 * g);
      }

      float Sl = 1.f, Tc1 = 1.f, Tc2 = 1.f;
      for (int it = 0; it < 30; it++) {
        // u-step: lane l = row l (only vv broadcasts hit LDS now)
        float a0 = 0.f, a1 = 0.f, a2 = 0.f, a3 = 0.f;
        #pragma unroll
        for (int g = 0; g < 28; g++) {
          float4 v4 = *(const float4*)(vv + 4 * g);  // broadcast
          a0 += kr[g].x * v4.x; a1 += kr[g].y * v4.y;
          a2 += kr[g].z * v4.z; a3 += kr[g].w * v4.w;
        }
        float S = (a0 + a1) + (a2 + a3);
        Sl = S;
        float ul = a_l * __builtin_amdgcn_rcpf(S);
        if (l < 48) uv[l] = ul;
        __asm__ volatile("s_waitcnt lgkmcnt(0)" ::: "memory");
        // v-step: lane l = cols l and l+64
        float p0 = 0.f, p1 = 0.f, q0 = 0.f, q1 = 0.f;
        #pragma unroll
        for (int g = 0; g < 12; g++) {
          float4 u4 = *(const float4*)(uv + 4 * g);  // broadcast
          p0 += kc1[g].x * u4.x + kc1[g].z * u4.z;
          p1 += kc1[g].y * u4.y + kc1[g].w * u4.w;
          q0 += kc2[g].x * u4.x + kc2[g].z * u4.z;
          q1 += kc2[g].y * u4.y + kc2[g].w * u4.w;
        }
        float T1 = p0 + p1, T2 = q0 + q1;
        Tc1 = T1; Tc2 = T2;
        vv[l] = b1w * __builtin_amdgcn_rcpf(T1);
        if (j2ok) vv[c2] = b2w * __builtin_amdgcn_rcpf(T2);
        __asm__ volatile("s_waitcnt lgkmcnt(0)" ::: "memory");
      }
      // dual value, 64-lane butterfly
      float val = (l < n0) ? inv_n0 * (rv[l] - __logf(Sl)) : 0.f;
      if (l < n1) val += inv_n1 * (cv[l] - __logf(Tc1));
      if (j2ok && c2 < n1) val += inv_n1 * (cv[c2] - __logf(Tc2));
      #pragma unroll
      for (int d = 1; d < 64; d <<= 1) val += __shfl_xor(val, d);
      if (l == 0) dcross[b] = EPS * val;
    }
  } else {
    // ================= rep / MLP path =================
    const int b = bid - 64;
    float* repv = (float*)smem;               // [1536]
    float* afl  = (float*)(smem + 8192);      // [128]
    float* bfl  = (float*)(smem + 8704);      // [128]
    float* red  = (float*)(smem + 9216);      // scratch

    if (t < 128) {
      int a_ = amask[b*128 + t], tt_ = ttid[b*128 + t];
      afl[t] = (a_ == 1 && tt_ == 0) ? 1.0f : 0.0f;
      bfl[t] = (a_ == 1 && tt_ == 1) ? 1.0f : 0.0f;
    }
    __syncthreads();
    if (t < 64) {
      float s = afl[t] + afl[t + 64];
      #pragma unroll
      for (int d = 32; d > 0; d >>= 1) s += __shfl_down(s, d);
      if (t == 0) red[0] = s;
    } else if (t < 128) {
      int l = t - 64;
      float s = bfl[l] + bfl[l + 64];
      #pragma unroll
      for (int d = 32; d > 0; d >>= 1) s += __shfl_down(s, d);
      if (l == 0) red[1] = s;
    }
    __syncthreads();
    const float n0 = fmaxf(red[0], 1.0f), n1 = fmaxf(red[1], 1.0f);
    if (t == 0) { cnt[b*2] = n0; cnt[b*2 + 1] = n1; }

    const float* Hb = H + (size_t)b * (128 * 768);
    // mean pool: 384 threads x float2 columns, deep unroll for ILP
    if (t < 384) {
      const float* cp = Hb + 2 * t;
      float s0x = 0.f, s0y = 0.f, s1x = 0.f, s1y = 0.f;
      #pragma unroll 16
      for (int i = 0; i < 128; i++) {
        float2 h = *(const float2*)(cp + i * 768);
        float av = afl[i], bv = bfl[i];
        s0x += av * h.x; s0y += av * h.y;
        s1x += bv * h.x; s1y += bv * h.y;
      }
      repv[768 + 2*t]     = s0x / n0 - s1x / n1;
      repv[768 + 2*t + 1] = s0y / n0 - s1y / n1;
      float2 h0 = *(const float2*)(cp);   // row 0 = cls (L1 hit)
      repv[2*t] = h0.x; repv[2*t + 1] = h0.y;
    }
    __syncthreads();

    const int klane = t & 63, og = t >> 6;
    float4 rr[6];
    #pragma unroll
    for (int c4 = 0; c4 < 6; c4++)
      rr[c4] = *(const float4*)(repv + c4 * 256 + klane * 4);
    const float gg = 1.0f / (1.0f + __expf(-gate[0]));
    // dual-row matvec: 2 independent load streams per iteration
    for (int oo = og; oo < 320; oo += 16) {
      const int o1 = oo + 8;
      const float* w0p = (oo < 256) ? (Wc + (size_t)oo * 1536)
                                    : (Ws + (size_t)(oo - 256) * 1536);
      const float* w1p = (o1 < 256) ? (Wc + (size_t)o1 * 1536)
                                    : (Ws + (size_t)(o1 - 256) * 1536);
      float sa = 0.f, sb = 0.f;
      #pragma unroll
      for (int c4 = 0; c4 < 6; c4++) {
        float4 wa = *(const float4*)(w0p + c4 * 256 + klane * 4);
        float4 wb = *(const float4*)(w1p + c4 * 256 + klane * 4);
        sa += rr[c4].x * wa.x + rr[c4].y * wa.y + rr[c4].z * wa.z + rr[c4].w * wa.w;
        sb += rr[c4].x * wb.x + rr[c4].y * wb.y + rr[c4].z * wb.z + rr[c4].w * wb.w;
      }
      #pragma unroll
      for (int d = 32; d > 0; d >>= 1) { sa += __shfl_down(sa, d); sb += __shfl_down(sb, d); }
      if (klane == 0) {
        float ba = (oo < 256) ? bc[oo] : bs[oo - 256];
        float bb = (o1 < 256) ? bc[o1] : bs[o1 - 256];
        fused[b * 320 + oo] = (sa + ba) * ((oo < 256) ? (1.0f - gg) : gg);
        fused[b * 320 + o1] = (sb + bb) * ((o1 < 256) ? (1.0f - gg) : gg);
      }
    }
  }

  // ================= fused finisher (replaces k_final) =================
  __syncthreads();                       // all block stores drained (vmcnt 0)
  if (t == 0) {
    __threadfence();                     // release: make this block's writes device-visible
    unsigned old = atomicAdd(ticket, 1u);
    smflag = ((old & 127u) == 127u) ? 1 : 0;   // exactly one block per launch, any initial value
  }
  __syncthreads();
  if (smflag) {
    __threadfence();                     // acquire: invalidate caches before reading peers' data
    const volatile float* vfused  = fused;
    const volatile float* vdcross = dcross;
    const volatile float* vcnt    = cnt;
    const int w = t >> 6, lane = t & 63;
    for (int b = w; b < 64; b += 8) {
      float cn0 = vcnt[b*2], cn1 = vcnt[b*2 + 1];
      float f320 = vdcross[b] - 0.5f * (EPS * __logf(cn0) + EPS * __logf(cn1) + 0.002f);
      float fv[5];
      #pragma unroll
      for (int c = 0; c < 5; c++) fv[c] = vfused[b * 320 + c * 64 + lane];
      float s = ((fv[0] + fv[1]) + (fv[2] + fv[3])) + fv[4];
      if (lane == 0) s += f320;
      #pragma unroll
      for (int d = 1; d < 64; d <<= 1) s += __shfl_xor(s, d);
      const float mu = s * (1.0f / 321.0f);
      float v = 0.f;
      #pragma unroll
      for (int c = 0; c < 5; c++) { float dd = fv[c] - mu; v += dd * dd; }
      if (lane == 0) { float dd = f320 - mu; v += dd * dd; }
      #pragma unroll
      for (int d = 1; d < 64; d <<= 1) v += __shfl_xor(v, d);
      const float rstd = rsqrtf(v * (1.0f / 321.0f) + 1e-5f);
      float p0 = 0.f, p1 = 0.f;
      #pragma unroll
      for (int c = 0; c < 5; c++) {
        int i = c * 64 + lane;
        float h = (fv[c] - mu) * rstd * lnw[i] + lnb[i];
        p0 += h * Wcls[i];
        p1 += h * Wcls[321 + i];
      }
      if (lane == 0) {
        float h = (f320 - mu) * rstd * lnw[320] + lnb[320];
        p0 += h * Wcls[320];
        p1 += h * Wcls[641];
      }
      #pragma unroll
      for (int d = 1; d < 64; d <<= 1) { p0 += __shfl_xor(p0, d); p1 += __shfl_xor(p1, d); }
      if (lane == 0) {
        out[b * 2]     = p0 + bcls[0];
        out[b * 2 + 1] = p1 + bcls[1];
      }
    }
  }
}

extern "C" void kernel_launch(void* const* d_in, const int* in_sizes, int n_in,
                              void* d_out, int out_size, void* d_ws, size_t ws_size,
                              hipStream_t stream)
{
  (void)in_sizes; (void)n_in; (void)out_size; (void)ws_size;
  const float* H    = (const float*)d_in[0];
  const int*   tt   = (const int*)d_in[1];
  const int*   am   = (const int*)d_in[2];
  const float* Wc   = (const float*)d_in[3];
  const float* bc   = (const float*)d_in[4];
  const float* Ws   = (const float*)d_in[5];
  const float* bs   = (const float*)d_in[6];
  const float* gate = (const float*)d_in[7];
  const float* lnw  = (const float*)d_in[8];
  const float* lnb  = (const float*)d_in[9];
  const float* Wcls = (const float*)d_in[10];
  const float* bcls = (const float*)d_in[11];
  float* out = (float*)d_out;

  float* dcross = (float*)d_ws;                    // 64
  float* cntv   = dcross + 64;                     // 128
  float* fusedv = cntv + 128;                      // 64*320
  unsigned* ticket = (unsigned*)(fusedv + 64 * 320);  // 1 (poison-tolerant mod-128)

  k_mega<<<dim3(128), dim3(512), 0, stream>>>(H, tt, am, Wc, bc, Ws, bs, gate,
                                              lnw, lnb, Wcls, bcls,
                                              dcross, cntv, fusedv, ticket, out);
}

// Round 2
// 156.729 us; speedup vs baseline: 1.0229x; 1.0229x over previous
//
#include <hip/hip_runtime.h>
#include <math.h>

#define EPS 0.05f
#define INV_EPS 20.0f
#define BIGF 1e30f

typedef short bf16x8 __attribute__((ext_vector_type(8)));
typedef float f32x4 __attribute__((ext_vector_type(4)));

__device__ __forceinline__ unsigned f2bf(float x) {
  unsigned u = __float_as_uint(x);
  return (u + 0x7fffu + ((u >> 16) & 1u)) >> 16;  // RNE f32->bf16
}
__device__ __forceinline__ unsigned pk2(float a, float b) {
  return (f2bf(a) & 0xffffu) | (f2bf(b) << 16);
}

struct Q4 { float4 a, b, c, d; };
__device__ __forceinline__ void loadQ(Q4& q, const float* p) {
  q.a = *(const float4*)p;       q.b = *(const float4*)(p + 4);
  q.c = *(const float4*)(p + 8); q.d = *(const float4*)(p + 12);
}
// pack 16 f32 -> bf16, store 32B to LDS, accumulate bf16-rounded square-sum
__device__ __forceinline__ void packQ(short* dst, const Q4& q, float& sq) {
  uint4 w0, w1;
  w0.x = pk2(q.a.x, q.a.y); w0.y = pk2(q.a.z, q.a.w);
  w0.z = pk2(q.b.x, q.b.y); w0.w = pk2(q.b.z, q.b.w);
  w1.x = pk2(q.c.x, q.c.y); w1.y = pk2(q.c.z, q.c.w);
  w1.z = pk2(q.d.x, q.d.y); w1.w = pk2(q.d.z, q.d.w);
  unsigned ws[8] = {w0.x, w0.y, w0.z, w0.w, w1.x, w1.y, w1.z, w1.w};
  #pragma unroll
  for (int k = 0; k < 8; k++) {
    float lo = __uint_as_float(ws[k] << 16);
    float hi = __uint_as_float(ws[k] & 0xffff0000u);
    sq += lo * lo + hi * hi;
  }
  *(uint4*)dst = w0;
  *(uint4*)(dst + 8) = w1;
}

// ---- LDS arena (bytes). Aliasing by phase lifetime:
#define S_HSA   0        // short[160][72] = 23040
#define S_HSB   23040    //               -> 46080
#define S_KT    0        // float[112][52] = 23296 (alias Hs, dead by then)
#define S_KR    46080    // float[48][116] = 22272 -> 68352
#define S_DSL   68352    // f32[160] -> 68992 (compact diag: [0,48)=A, [48,160)=B)
#define S_IA    68992    // int[48]  -> 69184
#define S_IB    69184    // int[112] -> 69632
#define S_RV    69632    // f32[48]  -> 69824
#define S_CV    69824    // f32[112] -> 70272
#define S_UV    70272    // f32[48]  -> 70464
#define S_VV    70464    // f32[112] -> 70912
#define S_CNT   70912    // int[4]   -> 70928
#define SMEM_SZ 70960

// single-batch LayerNorm + classifier, one wave (64 lanes)
__device__ __forceinline__ void finish_batch(int b, int lane,
    const float* __restrict__ fusedv, const float* __restrict__ dxv,
    const float* __restrict__ lnw, const float* __restrict__ lnb,
    const float* __restrict__ Wcls, const float* __restrict__ bcls,
    float* __restrict__ out)
{
  float f320 = __hip_atomic_load(dxv + b, __ATOMIC_RELAXED, __HIP_MEMORY_SCOPE_AGENT);
  float fv[5];
  #pragma unroll
  for (int c = 0; c < 5; c++)
    fv[c] = __hip_atomic_load(fusedv + b * 320 + c * 64 + lane,
                              __ATOMIC_RELAXED, __HIP_MEMORY_SCOPE_AGENT);
  float s = ((fv[0] + fv[1]) + (fv[2] + fv[3])) + fv[4];
  if (lane == 0) s += f320;
  #pragma unroll
  for (int d = 1; d < 64; d <<= 1) s += __shfl_xor(s, d);
  const float mu = s * (1.0f / 321.0f);
  float v = 0.f;
  #pragma unroll
  for (int c = 0; c < 5; c++) { float dd = fv[c] - mu; v += dd * dd; }
  if (lane == 0) { float dd = f320 - mu; v += dd * dd; }
  #pragma unroll
  for (int d = 1; d < 64; d <<= 1) v += __shfl_xor(v, d);
  const float rstd = rsqrtf(v * (1.0f / 321.0f) + 1e-5f);
  float p0 = 0.f, p1 = 0.f;
  #pragma unroll
  for (int c = 0; c < 5; c++) {
    int i = c * 64 + lane;
    float h = (fv[c] - mu) * rstd * lnw[i] + lnb[i];
    p0 += h * Wcls[i];
    p1 += h * Wcls[321 + i];
  }
  if (lane == 0) {
    float h = (f320 - mu) * rstd * lnw[320] + lnb[320];
    p0 += h * Wcls[320];
    p1 += h * Wcls[641];
  }
  #pragma unroll
  for (int d = 1; d < 64; d <<= 1) { p0 += __shfl_xor(p0, d); p1 += __shfl_xor(p1, d); }
  if (lane == 0) {
    out[b * 2]     = p0 + bcls[0];
    out[b * 2 + 1] = p1 + bcls[1];
  }
}

__global__ __launch_bounds__(512, 2)
void k_mega(const float* __restrict__ H, const int* __restrict__ ttid,
            const int* __restrict__ amask,
            const float* __restrict__ Wc, const float* __restrict__ bc,
            const float* __restrict__ Ws, const float* __restrict__ bs,
            const float* __restrict__ gate,
            const float* __restrict__ lnw, const float* __restrict__ lnb,
            const float* __restrict__ Wcls, const float* __restrict__ bcls,
            float* __restrict__ dcross, float* __restrict__ fused,
            unsigned* __restrict__ ticket, float* __restrict__ out)
{
  __shared__ __align__(16) char smem[SMEM_SZ];
  const int t = threadIdx.x;
  const int bid = blockIdx.x;

  if (bid < 64) {
    // ================= compact-support Sinkhorn =================
    const int b = bid;
    short*  HsA  = (short*)(smem + S_HSA);
    short*  HsB  = (short*)(smem + S_HSB);
    float*  KT   = (float*)(smem + S_KT);
    float*  Kr   = (float*)(smem + S_KR);
    float*  dslot= (float*)(smem + S_DSL);
    int*    ia   = (int*)(smem + S_IA);
    int*    ib   = (int*)(smem + S_IB);
    float*  rv   = (float*)(smem + S_RV);
    float*  cv   = (float*)(smem + S_CV);
    float*  uv   = (float*)(smem + S_UV);
    float*  vv   = (float*)(smem + S_VV);
    int*    cnts = (int*)(smem + S_CNT);

    const int lane = t & 63;
    const int w = t >> 6;

    // ---- Phase A: compact index lists via ballot prefix-sum ----
    int flagA = 0, flagB = 0;
    unsigned long long mA = 0, mB = 0;
    if (t < 128) {
      int a_ = amask[b*128 + t], tt_ = ttid[b*128 + t];
      flagA = (a_ == 1 && tt_ == 0);
      flagB = (a_ == 1 && tt_ == 1);
      mA = __ballot(flagA);
      mB = __ballot(flagB);
      if (lane == 0) { cnts[w] = __popcll(mA); cnts[2 + w] = __popcll(mB); }
    }
    __syncthreads();
    const int n0 = cnts[0] + cnts[1];   // <= 47
    const int n1 = cnts[2] + cnts[3];   // <= 112
    if (t < 128) {
      int offA = (w == 1) ? cnts[0] : 0;
      int offB = (w == 1) ? cnts[2] : 0;
      unsigned long long below = (1ull << lane) - 1ull;
      if (flagA) ia[offA + __popcll(mA & below)] = t;
      if (flagB) ib[offB + __popcll(mB & below)] = t;
    }
    for (int e = t; e < 48 * 116; e += 512) Kr[e] = BIGF;   // prefill
    __syncthreads();   // ia/ib + prefill visible

    // ---- Phase B: compact Gram = A-rows x B-rows, bf16 MFMA ----
    // slots: [0,48) = ia rows, [48,160) = ib rows. threads: slot t>>2 x 16 cols;
    // wave 7 (no MFMA tiles) additionally stages slots 128..159 (2 thr x 32 cols).
    const int wv = t >> 6;
    const int fm = lane & 15, fg = lane >> 4;
    const float* Hb = H + (size_t)b * (128 * 768);

    const int p = t >> 2, sc0 = (t & 3) * 16;
    int myrow;
    if (p < 48) myrow = (p < n0) ? ia[p] : 0;
    else { int q = p - 48; myrow = (q < n1) ? ib[q] : 0; }
    const float* srcP = Hb + myrow * 768 + sc0;

    const int lo7 = t - 448;
    const bool w7 = (t >= 448);
    int p2 = 0, sc2 = 0;
    const float* srcP2 = Hb;
    if (w7) {
      p2 = 128 + (lo7 >> 1); sc2 = (lo7 & 1) * 32;
      int q = p2 - 48;
      int r2 = (q < n1) ? ib[q] : 0;
      srcP2 = Hb + r2 * 768 + sc2;
    }

    f32x4 acc[3];
    #pragma unroll
    for (int r = 0; r < 3; r++) { acc[r][0]=0.f; acc[r][1]=0.f; acc[r][2]=0.f; acc[r][3]=0.f; }

    float sq = 0.f, sq2 = 0.f;
    Q4 pa, pb, xa0, xa1, xb0, xb1;
    loadQ(pa, srcP);                                    // chunk 0
    if (w7) { loadQ(xa0, srcP2); loadQ(xa1, srcP2 + 16); }
    packQ(HsA + p * 72 + sc0, pa, sq);
    if (w7) { packQ(HsA + p2 * 72 + sc2, xa0, sq2); packQ(HsA + p2 * 72 + sc2 + 16, xa1, sq2); }
    loadQ(pb, srcP + 64);                               // chunk 1
    if (w7) { loadQ(xb0, srcP2 + 64); loadQ(xb1, srcP2 + 80); }

    for (int kc = 0; kc < 12; kc++) {
      __syncthreads();     // chunk kc visible in cur; prior reads of nxt done
      short* cur = (kc & 1) ? HsB : HsA;
      short* nxt = (kc & 1) ? HsA : HsB;
      if ((kc & 1) == 0) {
        if (kc < 10) {     // prefetch chunk kc+2
          loadQ(pa, srcP + (kc + 2) * 64);
          if (w7) { loadQ(xa0, srcP2 + (kc + 2) * 64); loadQ(xa1, srcP2 + (kc + 2) * 64 + 16); }
        }
        if (kc < 11) {     // store chunk kc+1
          packQ(nxt + p * 72 + sc0, pb, sq);
          if (w7) { packQ(nxt + p2 * 72 + sc2, xb0, sq2); packQ(nxt + p2 * 72 + sc2 + 16, xb1, sq2); }
        }
      } else {
        if (kc < 10) {
          loadQ(pb, srcP + (kc + 2) * 64);
          if (w7) { loadQ(xb0, srcP2 + (kc + 2) * 64); loadQ(xb1, srcP2 + (kc + 2) * 64 + 16); }
        }
        if (kc < 11) {
          packQ(nxt + p * 72 + sc0, pa, sq);
          if (w7) { packQ(nxt + p2 * 72 + sc2, xa0, sq2); packQ(nxt + p2 * 72 + sc2 + 16, xa1, sq2); }
        }
      }
      if (wv < 7) {        // 3 row-tiles x col-tile wv, 21 tiles total
        #pragma unroll
        for (int ks = 0; ks < 2; ks++) {
          bf16x8 bfr = *(const bf16x8*)(cur + (48 + wv * 16 + fm) * 72 + ks * 32 + fg * 8);
          #pragma unroll
          for (int r = 0; r < 3; r++) {
            bf16x8 afr = *(const bf16x8*)(cur + (r * 16 + fm) * 72 + ks * 32 + fg * 8);
            acc[r] = __builtin_amdgcn_mfma_f32_16x16x32_bf16(afr, bfr, acc[r], 0, 0, 0);
          }
        }
      }
    }
    // compact diagonal from staging square-sums
    {
      float s = sq;
      s += __shfl_xor(s, 1); s += __shfl_xor(s, 2);
      if ((t & 3) == 0) dslot[p] = s;
      if (w7) {
        float s2 = sq2;
        s2 += __shfl_xor(s2, 1);
        if (!(lo7 & 1)) dslot[p2] = s2;
      }
    }
    __syncthreads();       // acc/diag complete; Hs still live but unread now

    // ---- epilogue: Ce = sqrt(dA+dB-2G)/eps straight from f32 accumulators ----
    if (wv < 7) {
      int j = wv * 16 + fm;
      if (j < n1) {
        float dj = dslot[48 + j];
        #pragma unroll
        for (int r = 0; r < 3; r++) {
          #pragma unroll
          for (int q = 0; q < 4; q++) {
            int i = r * 16 + fg * 4 + q;
            if (i < n0) {
              float d2 = fmaxf(dslot[i] + dj - 2.0f * acc[r][q], 1e-6f);
              Kr[i * 116 + j] = sqrtf(d2) * INV_EPS;
            }
          }
        }
      }
    }
    __syncthreads();

    // ---- Phase C: shifts r/c, K transform, KT build ----
    if (t < 192) {  // r_i = min_j Ce
      int r = t >> 2, c = t & 3;
      const float* row = Kr + r * 116 + c * 28;
      float mn = BIGF;
      #pragma unroll
      for (int g = 0; g < 7; g++) {
        float4 x = *(const float4*)(row + g * 4);
        mn = fminf(mn, fminf(fminf(x.x, x.y), fminf(x.z, x.w)));
      }
      mn = fminf(mn, __shfl_xor(mn, 1));
      mn = fminf(mn, __shfl_xor(mn, 2));
      if (c == 0) rv[r] = mn;
    }
    __syncthreads();
    if (t < 448) {  // c_j = min_{i<n0} (Ce - r_i)
      int cl = t >> 2, rr = t & 3;
      float mn = BIGF;
      #pragma unroll
      for (int g = 0; g < 12; g++) {
        int i = rr * 12 + g;
        float v = (i < n0) ? (Kr[i * 116 + cl] - rv[i]) : BIGF;
        mn = fminf(mn, v);
      }
      mn = fminf(mn, __shfl_xor(mn, 1));
      mn = fminf(mn, __shfl_xor(mn, 2));
      if (rr == 0) cv[cl] = mn;
    }
    __syncthreads();
    for (int i = t >> 7; i < 48; i += 4) {  // K = exp(min(r+c-Ce,0)), in place
      float ri = rv[i];
      for (int j = t & 127; j < 112; j += 128) {
        float ce = Kr[i * 116 + j];
        Kr[i * 116 + j] = __expf(fminf(ri + cv[j] - ce, 0.f));
      }
    }
    __syncthreads();       // Hs dead -> KT
    for (int i = t >> 7; i < 48; i += 4) {  // col-major copy for v-step
      int j = t & 127;
      if (j < 112) KT[j * 52 + i] = Kr[i * 116 + j];
    }
    const float inv_n0 = 1.0f / (float)n0;
    const float inv_n1 = 1.0f / (float)n1;
    if (t < 112) vv[t] = (t < n1) ? inv_n1 * __expf(-cv[t]) : 0.f;
    __syncthreads();       // last barrier before Phase D

    // ---- Phase D: single-wave, K register-resident, 30 scaling iterations ----
    if (t < 64) {
      const int l = t;
      const int r48 = (l < 48) ? l : 47;
      const float a_l = (l < n0) ? inv_n0 : 0.f;
      const int j2ok = (l + 64 < 112);
      const int c2 = j2ok ? (l + 64) : l;
      const float b1w = (l < n1) ? inv_n1 : 0.f;
      const float b2w = (j2ok && c2 < n1) ? inv_n1 : 0.f;
      const float* Krow = Kr + r48 * 116;
      const float* Kc1p = KT + l * 52;
      const float* Kc2p = KT + c2 * 52;

      float4 kr[28], kc1[12], kc2[12];
      #pragma unroll
      for (int g = 0; g < 28; g++) kr[g] = *(const float4*)(Krow + 4 * g);
      #pragma unroll
      for (int g = 0; g < 12; g++) {
        kc1[g] = *(const float4*)(Kc1p + 4 * g);
        kc2[g] = *(const float4*)(Kc2p + 4 * g);
      }

      float Sl = 1.f, Tc1 = 1.f, Tc2 = 1.f;
      for (int it = 0; it < 30; it++) {
        float a0 = 0.f, a1 = 0.f, a2 = 0.f, a3 = 0.f;
        #pragma unroll
        for (int g = 0; g < 28; g++) {
          float4 v4 = *(const float4*)(vv + 4 * g);  // broadcast
          a0 += kr[g].x * v4.x; a1 += kr[g].y * v4.y;
          a2 += kr[g].z * v4.z; a3 += kr[g].w * v4.w;
        }
        float S = (a0 + a1) + (a2 + a3);
        Sl = S;
        float ul = a_l * __builtin_amdgcn_rcpf(S);
        if (l < 48) uv[l] = ul;
        __asm__ volatile("s_waitcnt lgkmcnt(0)" ::: "memory");
        float p0 = 0.f, p1 = 0.f, q0 = 0.f, q1 = 0.f;
        #pragma unroll
        for (int g = 0; g < 12; g++) {
          float4 u4 = *(const float4*)(uv + 4 * g);  // broadcast
          p0 += kc1[g].x * u4.x + kc1[g].z * u4.z;
          p1 += kc1[g].y * u4.y + kc1[g].w * u4.w;
          q0 += kc2[g].x * u4.x + kc2[g].z * u4.z;
          q1 += kc2[g].y * u4.y + kc2[g].w * u4.w;
        }
        float T1 = p0 + p1, T2 = q0 + q1;
        Tc1 = T1; Tc2 = T2;
        vv[l] = b1w * __builtin_amdgcn_rcpf(T1);
        if (j2ok) vv[c2] = b2w * __builtin_amdgcn_rcpf(T2);
        __asm__ volatile("s_waitcnt lgkmcnt(0)" ::: "memory");
      }
      // dual value, 64-lane butterfly (all lanes end with the sum)
      float val = (l < n0) ? inv_n0 * (rv[l] - __logf(Sl)) : 0.f;
      if (l < n1) val += inv_n1 * (cv[l] - __logf(Tc1));
      if (j2ok && c2 < n1) val += inv_n1 * (cv[c2] - __logf(Tc2));
      #pragma unroll
      for (int d = 1; d < 64; d <<= 1) val += __shfl_xor(val, d);

      // publish f320 (cross-term minus collapsed self-terms) + ticket
      float f320 = EPS * val
                 - 0.5f * (EPS * __logf((float)n0) + EPS * __logf((float)n1) + 0.002f);
      if (l == 0) dcross[b] = f320;
      unsigned old = 0;
      if (l == 0) { __threadfence(); old = atomicAdd(&ticket[b], 1u); }
      old = __shfl(old, 0);
      if (old == 1) {        // second arriver finishes batch b
        __threadfence();
        finish_batch(b, l, fused, dcross, lnw, lnb, Wcls, bcls, out);
      }
    }
  } else {
    // ================= rep / MLP path =================
    const int b = bid - 64;
    float* repv = (float*)smem;               // [1536]
    float* afl  = (float*)(smem + 8192);      // [128]
    float* bfl  = (float*)(smem + 8704);      // [128]
    float* red  = (float*)(smem + 9216);      // scratch

    if (t < 128) {
      int a_ = amask[b*128 + t], tt_ = ttid[b*128 + t];
      afl[t] = (a_ == 1 && tt_ == 0) ? 1.0f : 0.0f;
      bfl[t] = (a_ == 1 && tt_ == 1) ? 1.0f : 0.0f;
    }
    __syncthreads();
    if (t < 64) {
      float s = afl[t] + afl[t + 64];
      #pragma unroll
      for (int d = 32; d > 0; d >>= 1) s += __shfl_down(s, d);
      if (t == 0) red[0] = s;
    } else if (t < 128) {
      int l = t - 64;
      float s = bfl[l] + bfl[l + 64];
      #pragma unroll
      for (int d = 32; d > 0; d >>= 1) s += __shfl_down(s, d);
      if (l == 0) red[1] = s;
    }
    __syncthreads();
    const float n0 = fmaxf(red[0], 1.0f), n1 = fmaxf(red[1], 1.0f);

    const float* Hb = H + (size_t)b * (128 * 768);
    if (t < 384) {   // mean pool: float2 columns, deep unroll for ILP
      const float* cp = Hb + 2 * t;
      float s0x = 0.f, s0y = 0.f, s1x = 0.f, s1y = 0.f;
      #pragma unroll 16
      for (int i = 0; i < 128; i++) {
        float2 h = *(const float2*)(cp + i * 768);
        float av = afl[i], bv = bfl[i];
        s0x += av * h.x; s0y += av * h.y;
        s1x += bv * h.x; s1y += bv * h.y;
      }
      repv[768 + 2*t]     = s0x / n0 - s1x / n1;
      repv[768 + 2*t + 1] = s0y / n0 - s1y / n1;
      float2 h0 = *(const float2*)(cp);   // row 0 = cls
      repv[2*t] = h0.x; repv[2*t + 1] = h0.y;
    }
    __syncthreads();

    const int klane = t & 63, og = t >> 6;
    float4 rr[6];
    #pragma unroll
    for (int c4 = 0; c4 < 6; c4++)
      rr[c4] = *(const float4*)(repv + c4 * 256 + klane * 4);
    const float gg = 1.0f / (1.0f + __expf(-gate[0]));
    for (int oo = og; oo < 320; oo += 16) {   // dual-row matvec
      const int o1 = oo + 8;
      const float* w0p = (oo < 256) ? (Wc + (size_t)oo * 1536)
                                    : (Ws + (size_t)(oo - 256) * 1536);
      const float* w1p = (o1 < 256) ? (Wc + (size_t)o1 * 1536)
                                    : (Ws + (size_t)(o1 - 256) * 1536);
      float sa = 0.f, sb = 0.f;
      #pragma unroll
      for (int c4 = 0; c4 < 6; c4++) {
        float4 wa = *(const float4*)(w0p + c4 * 256 + klane * 4);
        float4 wb = *(const float4*)(w1p + c4 * 256 + klane * 4);
        sa += rr[c4].x * wa.x + rr[c4].y * wa.y + rr[c4].z * wa.z + rr[c4].w * wa.w;
        sb += rr[c4].x * wb.x + rr[c4].y * wb.y + rr[c4].z * wb.z + rr[c4].w * wb.w;
      }
      #pragma unroll
      for (int d = 32; d > 0; d >>= 1) { sa += __shfl_down(sa, d); sb += __shfl_down(sb, d); }
      if (klane == 0) {
        float ba = (oo < 256) ? bc[oo] : bs[oo - 256];
        float bb = (o1 < 256) ? bc[o1] : bs[o1 - 256];
        fused[b * 320 + oo] = (sa + ba) * ((oo < 256) ? (1.0f - gg) : gg);
        fused[b * 320 + o1] = (sb + bb) * ((o1 < 256) ? (1.0f - gg) : gg);
      }
    }

    __syncthreads();                 // all fused stores drained
    if (t < 64) {
      unsigned old = 0;
      if (t == 0) { __threadfence(); old = atomicAdd(&ticket[b], 1u); }
      old = __shfl(old, 0);
      if (old == 1) {                // second arriver finishes batch b
        __threadfence();
        finish_batch(b, t, fused, dcross, lnw, lnb, Wcls, bcls, out);
      }
    }
  }
}

extern "C" void kernel_launch(void* const* d_in, const int* in_sizes, int n_in,
                              void* d_out, int out_size, void* d_ws, size_t ws_size,
                              hipStream_t stream)
{
  (void)in_sizes; (void)n_in; (void)out_size; (void)ws_size;
  const float* H    = (const float*)d_in[0];
  const int*   tt   = (const int*)d_in[1];
  const int*   am   = (const int*)d_in[2];
  const float* Wc   = (const float*)d_in[3];
  const float* bc   = (const float*)d_in[4];
  const float* Ws   = (const float*)d_in[5];
  const float* bs   = (const float*)d_in[6];
  const float* gate = (const float*)d_in[7];
  const float* lnw  = (const float*)d_in[8];
  const float* lnb  = (const float*)d_in[9];
  const float* Wcls = (const float*)d_in[10];
  const float* bcls = (const float*)d_in[11];
  float* out = (float*)d_out;

  float* dcross = (float*)d_ws;                        // 64
  float* fusedv = dcross + 64;                         // 64*320
  unsigned* ticket = (unsigned*)(fusedv + 64 * 320);   // 64 (zeroed per launch)

  hipMemsetAsync(ticket, 0, 64 * sizeof(unsigned), stream);
  k_mega<<<dim3(128), dim3(512), 0, stream>>>(H, tt, am, Wc, bc, Ws, bs, gate,
                                              lnw, lnb, Wcls, bcls,
                                              dcross, fusedv, ticket, out);
}

// Round 3
// 131.853 us; speedup vs baseline: 1.2159x; 1.1887x over previous
//
#include <hip/hip_runtime.h>
#include <math.h>

#define EPS 0.05f
#define INV_EPS 20.0f
#define BIGF 1e30f

typedef short bf16x8 __attribute__((ext_vector_type(8)));
typedef float f32x4 __attribute__((ext_vector_type(4)));

__device__ __forceinline__ unsigned f2bf(float x) {
  unsigned u = __float_as_uint(x);
  return (u + 0x7fffu + ((u >> 16) & 1u)) >> 16;  // RNE f32->bf16
}
__device__ __forceinline__ unsigned pk2(float a, float b) {
  return (f2bf(a) & 0xffffu) | (f2bf(b) << 16);
}
// uniform broadcast of lane src's float (pure VALU/SALU, no LDS)
__device__ __forceinline__ float rlane(float v, int lane) {
  return __uint_as_float(__builtin_amdgcn_readlane(__float_as_uint(v), lane));
}

struct Q4 { float4 a, b, c, d; };
__device__ __forceinline__ void loadQ(Q4& q, const float* p) {
  q.a = *(const float4*)p;       q.b = *(const float4*)(p + 4);
  q.c = *(const float4*)(p + 8); q.d = *(const float4*)(p + 12);
}
// pack 16 f32 -> bf16, store 32B to LDS, accumulate bf16-rounded square-sum
__device__ __forceinline__ void packQ(short* dst, const Q4& q, float& sq) {
  uint4 w0, w1;
  w0.x = pk2(q.a.x, q.a.y); w0.y = pk2(q.a.z, q.a.w);
  w0.z = pk2(q.b.x, q.b.y); w0.w = pk2(q.b.z, q.b.w);
  w1.x = pk2(q.c.x, q.c.y); w1.y = pk2(q.c.z, q.c.w);
  w1.z = pk2(q.d.x, q.d.y); w1.w = pk2(q.d.z, q.d.w);
  unsigned ws[8] = {w0.x, w0.y, w0.z, w0.w, w1.x, w1.y, w1.z, w1.w};
  #pragma unroll
  for (int k = 0; k < 8; k++) {
    float lo = __uint_as_float(ws[k] << 16);
    float hi = __uint_as_float(ws[k] & 0xffff0000u);
    sq += lo * lo + hi * hi;
  }
  *(uint4*)dst = w0;
  *(uint4*)(dst + 8) = w1;
}

// ---- LDS arena (bytes), phase-lifetime aliased:
#define S_HSA   0        // short[128][72] = 18432
#define S_HSB   18432    //               -> 36864
#define S_KR    36864    // float[48][116] = 22272 -> 59136
#define S_DIAG  59136    // f32[128]  -> 59648 (per H-row bf16 |h|^2)
#define S_DSL   59648    // f32[160]  -> 60288 (compact diag: [0,48)=A, [48,160)=B)
#define S_IA    60288    // int[48]   -> 60480
#define S_IB    60480    // int[112]  -> 60928
#define S_RV    60928    // f32[48]   -> 61120
#define S_CV    61120    // f32[112]  -> 61568
#define S_CNT   61568    // int[4]    -> 61584
#define SMEM_SZ 61600

// single-batch LayerNorm + classifier, one wave (64 lanes)
__device__ __forceinline__ void finish_batch(int b, int lane,
    const float* __restrict__ fusedv, const float* __restrict__ dxv,
    const float* __restrict__ lnw, const float* __restrict__ lnb,
    const float* __restrict__ Wcls, const float* __restrict__ bcls,
    float* __restrict__ out)
{
  float f320 = __hip_atomic_load(dxv + b, __ATOMIC_RELAXED, __HIP_MEMORY_SCOPE_AGENT);
  float fv[5];
  #pragma unroll
  for (int c = 0; c < 5; c++)
    fv[c] = __hip_atomic_load(fusedv + b * 320 + c * 64 + lane,
                              __ATOMIC_RELAXED, __HIP_MEMORY_SCOPE_AGENT);
  float s = ((fv[0] + fv[1]) + (fv[2] + fv[3])) + fv[4];
  if (lane == 0) s += f320;
  #pragma unroll
  for (int d = 1; d < 64; d <<= 1) s += __shfl_xor(s, d);
  const float mu = s * (1.0f / 321.0f);
  float v = 0.f;
  #pragma unroll
  for (int c = 0; c < 5; c++) { float dd = fv[c] - mu; v += dd * dd; }
  if (lane == 0) { float dd = f320 - mu; v += dd * dd; }
  #pragma unroll
  for (int d = 1; d < 64; d <<= 1) v += __shfl_xor(v, d);
  const float rstd = rsqrtf(v * (1.0f / 321.0f) + 1e-5f);
  float p0 = 0.f, p1 = 0.f;
  #pragma unroll
  for (int c = 0; c < 5; c++) {
    int i = c * 64 + lane;
    float h = (fv[c] - mu) * rstd * lnw[i] + lnb[i];
    p0 += h * Wcls[i];
    p1 += h * Wcls[321 + i];
  }
  if (lane == 0) {
    float h = (f320 - mu) * rstd * lnw[320] + lnb[320];
    p0 += h * Wcls[320];
    p1 += h * Wcls[641];
  }
  #pragma unroll
  for (int d = 1; d < 64; d <<= 1) { p0 += __shfl_xor(p0, d); p1 += __shfl_xor(p1, d); }
  if (lane == 0) {
    out[b * 2]     = p0 + bcls[0];
    out[b * 2 + 1] = p1 + bcls[1];
  }
}

__global__ __launch_bounds__(512)
void k_mega(const float* __restrict__ H, const int* __restrict__ ttid,
            const int* __restrict__ amask,
            const float* __restrict__ Wc, const float* __restrict__ bc,
            const float* __restrict__ Ws, const float* __restrict__ bs,
            const float* __restrict__ gate,
            const float* __restrict__ lnw, const float* __restrict__ lnb,
            const float* __restrict__ Wcls, const float* __restrict__ bcls,
            float* __restrict__ dcross, float* __restrict__ fused,
            unsigned* __restrict__ ticket, float* __restrict__ out)
{
  __shared__ __align__(16) char smem[SMEM_SZ];
  const int t = threadIdx.x;
  const int bid = blockIdx.x;

  if (bid < 64) {
    // ================= compact-support Sinkhorn =================
    const int b = bid;
    short*  HsA  = (short*)(smem + S_HSA);
    short*  HsB  = (short*)(smem + S_HSB);
    float*  Kr   = (float*)(smem + S_KR);
    float*  diag = (float*)(smem + S_DIAG);
    float*  dslot= (float*)(smem + S_DSL);
    int*    ia   = (int*)(smem + S_IA);
    int*    ib   = (int*)(smem + S_IB);
    float*  rv   = (float*)(smem + S_RV);
    float*  cv   = (float*)(smem + S_CV);
    int*    cnts = (int*)(smem + S_CNT);

    const int lane = t & 63;
    const int w = t >> 6;

    // ---- issue H chunk0/chunk1 loads FIRST (independent of masks) ----
    const float* Hb = H + (size_t)b * (128 * 768);
    const int srow = t >> 2, sc0 = (t & 3) * 16;
    const float* srcB = Hb + srow * 768 + sc0;
    Q4 pa, pb;
    loadQ(pa, srcB);
    loadQ(pb, srcB + 64);

    // ---- Phase A: compact index lists via ballot prefix-sum ----
    int flagA = 0, flagB = 0;
    unsigned long long mA = 0, mB = 0;
    if (t < 128) {
      int a_ = amask[b*128 + t], tt_ = ttid[b*128 + t];
      flagA = (a_ == 1 && tt_ == 0);
      flagB = (a_ == 1 && tt_ == 1);
      mA = __ballot(flagA);
      mB = __ballot(flagB);
      if (lane == 0) { cnts[w] = __popcll(mA); cnts[2 + w] = __popcll(mB); }
    }
    for (int e = t; e < 48 * 116; e += 512) Kr[e] = BIGF;   // prefill
    __syncthreads();
    const int n0 = cnts[0] + cnts[1];   // <= 47
    const int n1 = cnts[2] + cnts[3];   // <= 112
    if (t < 128) {
      int offA = (w == 1) ? cnts[0] : 0;
      int offB = (w == 1) ? cnts[2] : 0;
      unsigned long long below = (1ull << lane) - 1ull;
      if (flagA) ia[offA + __popcll(mA & below)] = t;
      if (flagB) ib[offB + __popcll(mB & below)] = t;
    }
    float sq = 0.f;
    packQ(HsA + srow * 72 + sc0, pa, sq);   // chunk 0 -> HsA
    __syncthreads();    // ia/ib + HsA chunk0 visible

    // ---- Phase B: linear staging of all 128 rows; compact MFMA via
    //      per-lane fragment row indices read once through ia/ib ----
    const int wv = t >> 6;
    const int fm = lane & 15, fg = lane >> 4;
    int ar0 = 0, ar1 = 0, ar2 = 0, br = 0;
    if (wv < 7) {
      ar0 = (fm      < n0) ? ia[fm]      : 0;
      ar1 = (16 + fm < n0) ? ia[16 + fm] : 0;
      ar2 = (32 + fm < n0) ? ia[32 + fm] : 0;
      br  = (wv * 16 + fm < n1) ? ib[wv * 16 + fm] : 0;
    }

    f32x4 acc[3];
    #pragma unroll
    for (int r = 0; r < 3; r++) { acc[r][0]=0.f; acc[r][1]=0.f; acc[r][2]=0.f; acc[r][3]=0.f; }

    for (int kc = 0; kc < 12; kc++) {
      if (kc) __syncthreads();   // chunk kc visible in cur; prior reads of nxt done
      short* cur = (kc & 1) ? HsB : HsA;
      short* nxt = (kc & 1) ? HsA : HsB;
      if (kc < 10) {             // prefetch chunk kc+2 (issue loads first)
        if ((kc & 1) == 0) loadQ(pa, srcB + (kc + 2) * 64);
        else               loadQ(pb, srcB + (kc + 2) * 64);
      }
      if (kc < 11) {             // pack+store chunk kc+1 into other buffer
        if ((kc & 1) == 0) packQ(nxt + srow * 72 + sc0, pb, sq);
        else               packQ(nxt + srow * 72 + sc0, pa, sq);
      }
      if (wv < 7) {              // 3 row-tiles x col-tile wv, 21 tiles total
        #pragma unroll
        for (int ks = 0; ks < 2; ks++) {
          bf16x8 bfr = *(const bf16x8*)(cur + br * 72 + ks * 32 + fg * 8);
          bf16x8 a0f = *(const bf16x8*)(cur + ar0 * 72 + ks * 32 + fg * 8);
          acc[0] = __builtin_amdgcn_mfma_f32_16x16x32_bf16(a0f, bfr, acc[0], 0, 0, 0);
          bf16x8 a1f = *(const bf16x8*)(cur + ar1 * 72 + ks * 32 + fg * 8);
          acc[1] = __builtin_amdgcn_mfma_f32_16x16x32_bf16(a1f, bfr, acc[1], 0, 0, 0);
          bf16x8 a2f = *(const bf16x8*)(cur + ar2 * 72 + ks * 32 + fg * 8);
          acc[2] = __builtin_amdgcn_mfma_f32_16x16x32_bf16(a2f, bfr, acc[2], 0, 0, 0);
        }
      }
    }
    // per-row bf16 square-sum -> diag
    {
      float s = sq;
      s += __shfl_xor(s, 1); s += __shfl_xor(s, 2);
      if ((t & 3) == 0) diag[srow] = s;
    }
    __syncthreads();
    if (t < 160)   // compact diag gather
      dslot[t] = diag[(t < 48) ? ((t < n0) ? ia[t] : 0)
                               : ((t - 48 < n1) ? ib[t - 48] : 0)];
    __syncthreads();

    // ---- epilogue: Ce = sqrt(dA+dB-2G)*INV_EPS straight from f32 acc ----
    if (wv < 7) {
      int j = wv * 16 + fm;
      if (j < n1) {
        float dj = dslot[48 + j];
        #pragma unroll
        for (int r = 0; r < 3; r++) {
          #pragma unroll
          for (int q = 0; q < 4; q++) {
            int i = r * 16 + fg * 4 + q;
            if (i < n0) {
              float d2 = fmaxf(dslot[i] + dj - 2.0f * acc[r][q], 1e-6f);
              Kr[i * 116 + j] = sqrtf(d2) * INV_EPS;
            }
          }
        }
      }
    }
    __syncthreads();

    // ---- Phase C: shifts r/c, K transform in place ----
    if (t < 192) {  // r_i = min_j Ce
      int r = t >> 2, c = t & 3;
      const float* row = Kr + r * 116 + c * 28;
      float mn = BIGF;
      #pragma unroll
      for (int g = 0; g < 7; g++) {
        float4 x = *(const float4*)(row + g * 4);
        mn = fminf(mn, fminf(fminf(x.x, x.y), fminf(x.z, x.w)));
      }
      mn = fminf(mn, __shfl_xor(mn, 1));
      mn = fminf(mn, __shfl_xor(mn, 2));
      if (c == 0) rv[r] = mn;
    }
    __syncthreads();
    if (t < 448) {  // c_j = min_{i<n0} (Ce - r_i)
      int cl = t >> 2, rr = t & 3;
      float mn = BIGF;
      #pragma unroll
      for (int g = 0; g < 12; g++) {
        int i = rr * 12 + g;
        float v = (i < n0) ? (Kr[i * 116 + cl] - rv[i]) : BIGF;
        mn = fminf(mn, v);
      }
      mn = fminf(mn, __shfl_xor(mn, 1));
      mn = fminf(mn, __shfl_xor(mn, 2));
      if (rr == 0) cv[cl] = mn;
    }
    __syncthreads();
    for (int i = t >> 7; i < 48; i += 4) {  // K = exp(min(r+c-Ce,0))
      float ri = rv[i];
      for (int j = t & 127; j < 112; j += 128) {
        float ce = Kr[i * 116 + j];
        Kr[i * 116 + j] = __expf(fminf(ri + cv[j] - ce, 0.f));
      }
    }
    __syncthreads();       // last barrier; waves 1-7 exit after this

    // ---- Phase D: single wave, all-register, LDS-free iterations ----
    if (t < 64) {
      const int l = t;
      const float inv_n0 = 1.0f / (float)n0;
      const float inv_n1 = 1.0f / (float)n1;
      const float a_l = (l < n0) ? inv_n0 : 0.f;
      const int j2ok = (l + 64 < 112);
      const int c2 = j2ok ? (l + 64) : l;            // clamped addr
      const float b1w = (l < n1) ? inv_n1 : 0.f;
      const float b2w = (j2ok && (l + 64 < n1)) ? inv_n1 : 0.f;

      // hoist row l of K (112 f32) and cols l, l+64 (48+48 f32) into registers
      float kf[112];
      {
        const float* Krow = Kr + ((l < 48) ? l : 47) * 116;
        #pragma unroll
        for (int g = 0; g < 28; g++) {
          float4 x = *(const float4*)(Krow + 4 * g);
          kf[4*g] = x.x; kf[4*g+1] = x.y; kf[4*g+2] = x.z; kf[4*g+3] = x.w;
        }
      }
      float kc1[48], kc2[48];
      #pragma unroll
      for (int i = 0; i < 48; i++) {
        kc1[i] = Kr[i * 116 + l];    // stride-29-word column reads, conflict-free
        kc2[i] = Kr[i * 116 + c2];
      }

      // initial v in registers (one LDS read of cv each)
      float v1 = (l < n1) ? inv_n1 * __expf(-cv[l]) : 0.f;
      float v2 = (j2ok && (l + 64 < n1)) ? inv_n1 * __expf(-cv[l + 64]) : 0.f;

      float Sl = 1.f, T1l = 1.f, T2l = 1.f, ul = 0.f;
      for (int it = 0; it < 30; it++) {
        // u-step: S_l = sum_j K[l][j] v_j  (v broadcast via readlane)
        float a0 = 0.f, a1 = 0.f, a2 = 0.f, a3 = 0.f;
        #pragma unroll
        for (int j = 0; j < 64; j += 4) {
          float s0 = rlane(v1, j),     s1 = rlane(v1, j + 1);
          float s2 = rlane(v1, j + 2), s3 = rlane(v1, j + 3);
          a0 += kf[j] * s0;     a1 += kf[j + 1] * s1;
          a2 += kf[j + 2] * s2; a3 += kf[j + 3] * s3;
        }
        #pragma unroll
        for (int j = 0; j < 48; j += 4) {
          float s0 = rlane(v2, j),     s1 = rlane(v2, j + 1);
          float s2 = rlane(v2, j + 2), s3 = rlane(v2, j + 3);
          a0 += kf[64 + j] * s0;     a1 += kf[65 + j] * s1;
          a2 += kf[66 + j] * s2;     a3 += kf[67 + j] * s3;
        }
        float S = (a0 + a1) + (a2 + a3);
        Sl = S;
        ul = a_l * __builtin_amdgcn_rcpf(S);
        // v-step: T_j = sum_i K[i][j] u_i  (u broadcast via readlane)
        float p0 = 0.f, p1 = 0.f, q0 = 0.f, q1 = 0.f;
        #pragma unroll
        for (int i = 0; i < 48; i += 2) {
          float s0 = rlane(ul, i), s1 = rlane(ul, i + 1);
          p0 += kc1[i] * s0;     q0 += kc2[i] * s0;
          p1 += kc1[i + 1] * s1; q1 += kc2[i + 1] * s1;
        }
        float T1 = p0 + p1, T2 = q0 + q1;
        T1l = T1; T2l = T2;
        v1 = b1w * __builtin_amdgcn_rcpf(T1);
        v2 = b2w * __builtin_amdgcn_rcpf(T2);
      }
      // dual value, 64-lane butterfly
      float val = (l < n0) ? inv_n0 * (rv[l] - __logf(Sl)) : 0.f;
      if (l < n1) val += inv_n1 * (cv[l] - __logf(T1l));
      if (j2ok && (l + 64 < n1)) val += inv_n1 * (cv[l + 64] - __logf(T2l));
      #pragma unroll
      for (int d = 1; d < 64; d <<= 1) val += __shfl_xor(val, d);

      float f320 = EPS * val
                 - 0.5f * (EPS * __logf((float)n0) + EPS * __logf((float)n1) + 0.002f);
      if (l == 0) dcross[b] = f320;
      unsigned old = 0;
      if (l == 0) { __threadfence(); old = atomicAdd(&ticket[b], 1u); }
      old = __shfl(old, 0);
      if (old == 1) {        // second arriver finishes batch b
        __threadfence();
        finish_batch(b, l, fused, dcross, lnw, lnb, Wcls, bcls, out);
      }
    }
  } else {
    // ================= rep / MLP path =================
    const int b = bid - 64;
    float* repv = (float*)smem;               // [1536]
    float* afl  = (float*)(smem + 8192);      // [128]
    float* bfl  = (float*)(smem + 8704);      // [128]
    float* red  = (float*)(smem + 9216);      // scratch

    if (t < 128) {
      int a_ = amask[b*128 + t], tt_ = ttid[b*128 + t];
      afl[t] = (a_ == 1 && tt_ == 0) ? 1.0f : 0.0f;
      bfl[t] = (a_ == 1 && tt_ == 1) ? 1.0f : 0.0f;
    }
    __syncthreads();
    if (t < 64) {
      float s = afl[t] + afl[t + 64];
      #pragma unroll
      for (int d = 32; d > 0; d >>= 1) s += __shfl_down(s, d);
      if (t == 0) red[0] = s;
    } else if (t < 128) {
      int l = t - 64;
      float s = bfl[l] + bfl[l + 64];
      #pragma unroll
      for (int d = 32; d > 0; d >>= 1) s += __shfl_down(s, d);
      if (l == 0) red[1] = s;
    }
    __syncthreads();
    const float n0 = fmaxf(red[0], 1.0f), n1 = fmaxf(red[1], 1.0f);

    const float* Hb = H + (size_t)b * (128 * 768);
    if (t < 384) {   // mean pool: float2 columns, deep unroll for ILP
      const float* cp = Hb + 2 * t;
      float s0x = 0.f, s0y = 0.f, s1x = 0.f, s1y = 0.f;
      #pragma unroll 16
      for (int i = 0; i < 128; i++) {
        float2 h = *(const float2*)(cp + i * 768);
        float av = afl[i], bv = bfl[i];
        s0x += av * h.x; s0y += av * h.y;
        s1x += bv * h.x; s1y += bv * h.y;
      }
      repv[768 + 2*t]     = s0x / n0 - s1x / n1;
      repv[768 + 2*t + 1] = s0y / n0 - s1y / n1;
      float2 h0 = *(const float2*)(cp);   // row 0 = cls
      repv[2*t] = h0.x; repv[2*t + 1] = h0.y;
    }
    __syncthreads();

    const int klane = t & 63, og = t >> 6;
    float4 rr[6];
    #pragma unroll
    for (int c4 = 0; c4 < 6; c4++)
      rr[c4] = *(const float4*)(repv + c4 * 256 + klane * 4);
    const float gg = 1.0f / (1.0f + __expf(-gate[0]));
    for (int oo = og; oo < 320; oo += 16) {   // dual-row matvec
      const int o1 = oo + 8;
      const float* w0p = (oo < 256) ? (Wc + (size_t)oo * 1536)
                                    : (Ws + (size_t)(oo - 256) * 1536);
      const float* w1p = (o1 < 256) ? (Wc + (size_t)o1 * 1536)
                                    : (Ws + (size_t)(o1 - 256) * 1536);
      float sa = 0.f, sb = 0.f;
      #pragma unroll
      for (int c4 = 0; c4 < 6; c4++) {
        float4 wa = *(const float4*)(w0p + c4 * 256 + klane * 4);
        float4 wb = *(const float4*)(w1p + c4 * 256 + klane * 4);
        sa += rr[c4].x * wa.x + rr[c4].y * wa.y + rr[c4].z * wa.z + rr[c4].w * wa.w;
        sb += rr[c4].x * wb.x + rr[c4].y * wb.y + rr[c4].z * wb.z + rr[c4].w * wb.w;
      }
      #pragma unroll
      for (int d = 32; d > 0; d >>= 1) { sa += __shfl_down(sa, d); sb += __shfl_down(sb, d); }
      if (klane == 0) {
        float ba = (oo < 256) ? bc[oo] : bs[oo - 256];
        float bb = (o1 < 256) ? bc[o1] : bs[o1 - 256];
        fused[b * 320 + oo] = (sa + ba) * ((oo < 256) ? (1.0f - gg) : gg);
        fused[b * 320 + o1] = (sb + bb) * ((o1 < 256) ? (1.0f - gg) : gg);
      }
    }

    __syncthreads();                 // all fused stores drained
    if (t < 64) {
      unsigned old = 0;
      if (t == 0) { __threadfence(); old = atomicAdd(&ticket[b], 1u); }
      old = __shfl(old, 0);
      if (old == 1) {                // second arriver finishes batch b
        __threadfence();
        finish_batch(b, t, fused, dcross, lnw, lnb, Wcls, bcls, out);
      }
    }
  }
}

extern "C" void kernel_launch(void* const* d_in, const int* in_sizes, int n_in,
                              void* d_out, int out_size, void* d_ws, size_t ws_size,
                              hipStream_t stream)
{
  (void)in_sizes; (void)n_in; (void)out_size; (void)ws_size;
  const float* H    = (const float*)d_in[0];
  const int*   tt   = (const int*)d_in[1];
  const int*   am   = (const int*)d_in[2];
  const float* Wc   = (const float*)d_in[3];
  const float* bc   = (const float*)d_in[4];
  const float* Ws   = (const float*)d_in[5];
  const float* bs   = (const float*)d_in[6];
  const float* gate = (const float*)d_in[7];
  const float* lnw  = (const float*)d_in[8];
  const float* lnb  = (const float*)d_in[9];
  const float* Wcls = (const float*)d_in[10];
  const float* bcls = (const float*)d_in[11];
  float* out = (float*)d_out;

  float* dcross = (float*)d_ws;                        // 64
  float* fusedv = dcross + 64;                         // 64*320
  unsigned* ticket = (unsigned*)(fusedv + 64 * 320);   // 64 (zeroed per launch)

  hipMemsetAsync(ticket, 0, 64 * sizeof(unsigned), stream);
  k_mega<<<dim3(128), dim3(512), 0, stream>>>(H, tt, am, Wc, bc, Ws, bs, gate,
                                              lnw, lnb, Wcls, bcls,
                                              dcross, fusedv, ticket, out);
}